// Round 1
// baseline (2666.299 us; speedup 1.0000x reference)
//
#include <hip/hip_runtime.h>
#include <math.h>

constexpr int Bn  = 2;
constexpr int Cn  = 128;
constexpr int Hn  = 96;
constexpr int Wn  = 96;
constexpr int KKn = 9;
constexpr int HWn = Hn * Wn;        // 9216
constexpr int CHWn = Cn * HWn;      // 1179648
constexpr int KCn = Cn * KKn;       // 1152
constexpr float EPSn = 1e-5f;
constexpr int Pn = 8;               // pixels per block in dconv

// wT[ck*Cn + o] = w[o*KCn + ck]
__global__ __launch_bounds__(256) void transpose_w_kernel(
    const float* __restrict__ w, float* __restrict__ wT)
{
    int tid = blockIdx.x * 256 + threadIdx.x;
    if (tid >= Cn * KCn) return;
    int o  = tid % Cn;
    int ck = tid / Cn;
    wT[tid] = w[o * KCn + ck];
}

// offset conv: om = conv(x, ow, dil) + ob ; channels 0..17 -> offb, 18..26 -> sigmoid -> maskb
__global__ __launch_bounds__(256) void offconv_kernel(
    const float* __restrict__ x, const float* __restrict__ ow,
    const float* __restrict__ ob, float* __restrict__ offb,
    float* __restrict__ maskb, int dil)
{
    int tid = blockIdx.x * 256 + threadIdx.x;
    if (tid >= Bn * 27 * HWn) return;
    int wx = tid % Wn;
    int t  = tid / Wn;
    int hy = t % Hn;  t /= Hn;
    int oc = t % 27;
    int b  = t / 27;

    int   idx[KKn];
    float msk[KKn];
    bool allv = true;
#pragma unroll
    for (int k = 0; k < KKn; ++k) {
        int iy = hy + (k / 3 - 1) * dil;
        int ix = wx + (k % 3 - 1) * dil;
        bool val = (iy >= 0) & (iy < Hn) & (ix >= 0) & (ix < Wn);
        idx[k] = val ? iy * Wn + ix : 0;
        msk[k] = val ? 1.f : 0.f;
        allv = allv && val;
    }

    const float* xb = x + b * CHWn;
    const float* wr = ow + oc * KCn;
    float acc = ob[oc];
    if (allv) {
        for (int c = 0; c < Cn; ++c) {
            const float* xc = xb + c * HWn;
#pragma unroll
            for (int k = 0; k < KKn; ++k)
                acc += xc[idx[k]] * wr[c * KKn + k];
        }
    } else {
        for (int c = 0; c < Cn; ++c) {
            const float* xc = xb + c * HWn;
#pragma unroll
            for (int k = 0; k < KKn; ++k)
                acc += xc[idx[k]] * (wr[c * KKn + k] * msk[k]);
        }
    }

    int sp = hy * Wn + wx;
    if (oc < 18) {
        offb[(b * 18 + oc) * HWn + sp] = acc;
    } else {
        maskb[(b * 9 + (oc - 18)) * HWn + sp] = 1.f / (1.f + expf(-acc));
    }
}

// deformable conv + BN + relu + residual for Pn consecutive pixels per block.
// 128 threads: sampling phase -> thread = channel c; GEMM phase -> thread = out channel o.
__global__ __launch_bounds__(128) void dconv_kernel(
    const float* __restrict__ x, const float* __restrict__ offb,
    const float* __restrict__ maskb, const float* __restrict__ wT,
    const float* __restrict__ g, const float* __restrict__ bb,
    const float* __restrict__ mn, const float* __restrict__ vr,
    float* __restrict__ out, int dil)
{
    __shared__ float s[KCn * Pn];   // s[(c*9+k)*Pn + p]

    const int c = threadIdx.x;
    const int pix0 = blockIdx.x * Pn;
    const int b   = pix0 / HWn;
    const int rem = pix0 - b * HWn;
    const int hy  = rem / Wn;
    const int wx0 = rem - hy * Wn;

    const float* xb = x + b * CHWn + c * HWn;
    const int rowoff = hy * Wn;

    for (int p = 0; p < Pn; ++p) {
        const int wx = wx0 + p;
        const int sp = rowoff + wx;
        for (int k = 0; k < KKn; ++k) {
            float offy = offb[(b * 18 + 2 * k) * HWn + sp];
            float offx = offb[(b * 18 + 2 * k + 1) * HWn + sp];
            float mk   = maskb[(b * 9 + k) * HWn + sp];
            float py = (float)(hy + (k / 3 - 1) * dil) + offy;
            float px = (float)(wx + (k % 3 - 1) * dil) + offx;
            float y0f = floorf(py), x0f = floorf(px);
            float ly = py - y0f, lx = px - x0f;
            int y0 = (int)y0f, x0 = (int)x0f;
            float acc = 0.f;
#pragma unroll
            for (int dy = 0; dy < 2; ++dy) {
                float wy = dy ? ly : 1.f - ly;
                int yi = y0 + dy;
                bool yv = (yi >= 0) & (yi < Hn);
                int ycl = min(max(yi, 0), Hn - 1);
#pragma unroll
                for (int dx = 0; dx < 2; ++dx) {
                    float wxw = dx ? lx : 1.f - lx;
                    int xi = x0 + dx;
                    bool xv = (xi >= 0) & (xi < Wn);
                    int xcl = min(max(xi, 0), Wn - 1);
                    float vv = xb[ycl * Wn + xcl];
                    acc += (yv && xv) ? vv * wy * wxw : 0.f;
                }
            }
            s[(c * KKn + k) * Pn + p] = acc * mk;
        }
    }
    __syncthreads();

    // GEMM: acc[p] = sum_i s[i][p] * wT[i*Cn + o],  o = threadIdx.x
    float acc[Pn];
#pragma unroll
    for (int p = 0; p < Pn; ++p) acc[p] = 0.f;
    const float* wcol = wT + c;
#pragma unroll 4
    for (int i = 0; i < KCn; ++i) {
        float wv = wcol[i * Cn];
        const float* sp = &s[i * Pn];
#pragma unroll
        for (int p = 0; p < Pn; ++p) acc[p] += sp[p] * wv;
    }

    // epilogue: BN + relu + residual
    const int o = c;
    float sc = g[o] * rsqrtf(vr[o] + EPSn);
    float mm = mn[o], bo = bb[o];
    const float* resb = x + b * CHWn + o * HWn + rowoff;
    float* outb = out + b * CHWn + o * HWn + rowoff;
#pragma unroll
    for (int p = 0; p < Pn; ++p) {
        float y = (acc[p] - mm) * sc + bo;
        y = fmaxf(y, 0.f) + resb[wx0 + p];
        outb[wx0 + p] = y;
    }
}

extern "C" void kernel_launch(void* const* d_in, const int* in_sizes, int n_in,
                              void* d_out, int out_size, void* d_ws, size_t ws_size,
                              hipStream_t stream) {
    (void)in_sizes; (void)n_in; (void)out_size; (void)ws_size;

    const float* hu = (const float*)d_in[0];
    float* ws = (float*)d_ws;
    float* wT    = ws;                          // 3 * KCn*Cn = 442368 floats
    float* offb  = wT + 3 * KCn * Cn;           // Bn*18*HWn = 331776
    float* maskb = offb + Bn * 18 * HWn;        // Bn*9*HWn  = 165888
    float* a1    = maskb + Bn * 9 * HWn;        // Bn*CHWn   = 2359296
    float* a2    = a1 + Bn * CHWn;              // Bn*CHWn

    for (int i = 0; i < 3; ++i) {
        const float* wmat = (const float*)d_in[3 + 7 * i];
        transpose_w_kernel<<<(Cn * KCn + 255) / 256, 256, 0, stream>>>(
            wmat, wT + i * KCn * Cn);
    }

    const int dils[3] = {2, 4, 8};
    float* outs[3] = {a1, a2, (float*)d_out};
    const float* xin = hu;
    for (int i = 0; i < 3; ++i) {
        const float* ow  = (const float*)d_in[1 + 7 * i];
        const float* obv = (const float*)d_in[2 + 7 * i];
        const float* gv  = (const float*)d_in[4 + 7 * i];
        const float* bv  = (const float*)d_in[5 + 7 * i];
        const float* mv  = (const float*)d_in[6 + 7 * i];
        const float* vv  = (const float*)d_in[7 + 7 * i];

        offconv_kernel<<<(Bn * 27 * HWn + 255) / 256, 256, 0, stream>>>(
            xin, ow, obv, offb, maskb, dils[i]);
        dconv_kernel<<<(Bn * HWn) / Pn, 128, 0, stream>>>(
            xin, offb, maskb, wT + i * KCn * Cn, gv, bv, mv, vv,
            outs[i], dils[i]);
        xin = outs[i];
    }
}

// Round 2
// 585.921 us; speedup vs baseline: 4.5506x; 4.5506x over previous
//
#include <hip/hip_runtime.h>
#include <math.h>

constexpr int Bn  = 2;
constexpr int Cn  = 128;
constexpr int Hn  = 96;
constexpr int Wn  = 96;
constexpr int HWn = Hn * Wn;        // 9216
constexpr int CHWn = Cn * HWn;      // 1179648
constexpr int KCn = Cn * 9;         // 1152
constexpr float EPSn = 1e-5f;
constexpr int KPAD = 296;           // LDS row stride (shorts): 592B = 37*16B

typedef short bf16x8 __attribute__((ext_vector_type(8)));
typedef float f32x4  __attribute__((ext_vector_type(4)));

static __device__ inline short f2bf(float f) {
    union { float f; unsigned u; } v; v.f = f;
    unsigned r = v.u + 0x7fff + ((v.u >> 16) & 1);
    return (short)(r >> 16);
}

__global__ __launch_bounds__(256) void cvt_w_kernel(
    const float* __restrict__ w, short* __restrict__ wb)
{
    int t = blockIdx.x * 256 + threadIdx.x;   // 128*1152
    if (t < Cn * KCn) wb[t] = f2bf(w[t]);
}

__global__ __launch_bounds__(256) void cvt_ow_kernel(
    const float* __restrict__ ow, short* __restrict__ owb)
{
    int t = blockIdx.x * 256 + threadIdx.x;   // 32*1152
    if (t >= 32 * KCn) return;
    int row = t / KCn;
    owb[t] = (row < 27) ? f2bf(ow[t]) : (short)0;
}

// ---------------- offset conv (128 -> 27ch) as bf16 MFMA GEMM -------------
__global__ __launch_bounds__(256) void offconv_mfma(
    const float* __restrict__ x, const short* __restrict__ owb,
    const float* __restrict__ obv, float* __restrict__ offb,
    float* __restrict__ maskb, int dil)
{
    __shared__ short S[64][KPAD];
    const int tid = threadIdx.x;
    const int p   = tid & 63;
    const int grp = tid >> 6;
    const int pix0 = blockIdx.x * 64;
    const int b  = pix0 / HWn;
    const int sp = pix0 - b * HWn + p;
    const int hy = sp / Wn;
    const int wx = sp - hy * Wn;

    int   aof[9];
    float mk[9];
#pragma unroll
    for (int k = 0; k < 9; ++k) {
        int iy = hy + (k / 3 - 1) * dil;
        int ix = wx + (k % 3 - 1) * dil;
        bool v = (iy >= 0) && (iy < Hn) && (ix >= 0) && (ix < Wn);
        aof[k] = v ? iy * Wn + ix : 0;
        mk[k]  = v ? 1.f : 0.f;
    }

    f32x4 acc[2];
#pragma unroll
    for (int mf = 0; mf < 2; ++mf) { f32x4 z = {0.f,0.f,0.f,0.f}; acc[mf] = z; }

    const int l = p;
    for (int cc = 0; cc < 4; ++cc) {
        const float* xc = x + b * CHWn + (cc * 32 + grp * 8) * HWn;
#pragma unroll
        for (int i = 0; i < 36; ++i) {
            const int r0 = 2 * i, r1 = 2 * i + 1;
            const int k0 = r0 % 9, c0l = r0 / 9;
            const int k1 = r1 % 9, c1l = r1 / 9;
            float s0 = xc[c0l * HWn + aof[k0]] * mk[k0];
            float s1 = xc[c1l * HWn + aof[k1]] * mk[k1];
            unsigned pk = (unsigned)(unsigned short)f2bf(s0)
                        | ((unsigned)(unsigned short)f2bf(s1) << 16);
            *(unsigned*)&S[p][grp * 72 + r0] = pk;
        }
        __syncthreads();
        const short* warow = owb + (l & 15) * KCn + cc * 288 + ((l >> 4) * 8);
#pragma unroll
        for (int kk = 0; kk < 9; ++kk) {
            bf16x8 af0 = *(const bf16x8*)(warow + kk * 32);
            bf16x8 af1 = *(const bf16x8*)(warow + 16 * KCn + kk * 32);
            bf16x8 bfg = *(const bf16x8*)&S[grp * 16 + (l & 15)][kk * 32 + ((l >> 4) * 8)];
            acc[0] = __builtin_amdgcn_mfma_f32_16x16x32_bf16(af0, bfg, acc[0], 0, 0, 0);
            acc[1] = __builtin_amdgcn_mfma_f32_16x16x32_bf16(af1, bfg, acc[1], 0, 0, 0);
        }
        __syncthreads();
    }

    const int pix = pix0 + grp * 16 + (l & 15);
    const int spn = pix - b * HWn;
#pragma unroll
    for (int mf = 0; mf < 2; ++mf) {
#pragma unroll
        for (int r = 0; r < 4; ++r) {
            int oc = mf * 16 + ((l >> 4) << 2) + r;
            float val = acc[mf][r];
            if (oc < 18) {
                offb[(b * 18 + oc) * HWn + spn] = val + obv[oc];
            } else if (oc < 27) {
                float z = val + obv[oc];
                maskb[(b * 9 + (oc - 18)) * HWn + spn] = 1.f / (1.f + expf(-z));
            }
        }
    }
}

// ------- deformable conv + BN + ReLU + residual as bf16 MFMA GEMM ---------
__global__ __launch_bounds__(256) void dconv_mfma(
    const float* __restrict__ x, const float* __restrict__ offb,
    const float* __restrict__ maskb, const short* __restrict__ wb,
    const float* __restrict__ gv, const float* __restrict__ bv,
    const float* __restrict__ mv, const float* __restrict__ vv,
    float* __restrict__ out, int dil)
{
    __shared__ short S[64][KPAD];
    const int tid = threadIdx.x;
    const int p   = tid & 63;
    const int grp = tid >> 6;
    const int pix0 = blockIdx.x * 64;
    const int b  = pix0 / HWn;
    const int sp = pix0 - b * HWn + p;
    const int hy = sp / Wn;
    const int wx = sp - hy * Wn;

    // per-lane bilinear params for the 9 taps (compile-time indexed)
    float w00[9], w01[9], w10[9], w11[9];
    int   a00[9], a11[9], dxk[9];
#pragma unroll
    for (int k = 0; k < 9; ++k) {
        float offy = offb[(b * 18 + 2 * k) * HWn + sp];
        float offx = offb[(b * 18 + 2 * k + 1) * HWn + sp];
        float m    = maskb[(b * 9 + k) * HWn + sp];
        float py = (float)(hy + (k / 3 - 1) * dil) + offy;
        float px = (float)(wx + (k % 3 - 1) * dil) + offx;
        float y0f = floorf(py), x0f = floorf(px);
        float ly = py - y0f, lx = px - x0f;
        int y0 = (int)y0f, x0 = (int)x0f;
        float yv0 = (y0 >= 0 && y0 < Hn)      ? 1.f : 0.f;
        float yv1 = (y0 >= -1 && y0 < Hn - 1) ? 1.f : 0.f;
        float xv0 = (x0 >= 0 && x0 < Wn)      ? 1.f : 0.f;
        float xv1 = (x0 >= -1 && x0 < Wn - 1) ? 1.f : 0.f;
        float wy0 = (1.f - ly) * yv0 * m;
        float wy1 = ly * yv1 * m;
        float wxa = (1.f - lx) * xv0;
        float wxb = lx * xv1;
        w00[k] = wy0 * wxa; w01[k] = wy0 * wxb;
        w10[k] = wy1 * wxa; w11[k] = wy1 * wxb;
        int y0c = min(max(y0, 0), Hn - 1), y1c = min(max(y0 + 1, 0), Hn - 1);
        int x0c = min(max(x0, 0), Wn - 1), x1c = min(max(x0 + 1, 0), Wn - 1);
        a00[k] = y0c * Wn + x0c;
        a11[k] = y1c * Wn + x1c;
        dxk[k] = x1c - x0c;
    }

    f32x4 acc[2][4];
#pragma unroll
    for (int mf = 0; mf < 2; ++mf)
#pragma unroll
        for (int nf = 0; nf < 4; ++nf) { f32x4 z = {0.f,0.f,0.f,0.f}; acc[mf][nf] = z; }

    const int l = p;
    for (int cc = 0; cc < 4; ++cc) {
        const float* xc = x + b * CHWn + (cc * 32 + grp * 8) * HWn;
#pragma unroll
        for (int i = 0; i < 36; ++i) {
            const int r0 = 2 * i, r1 = 2 * i + 1;
            const int k0 = r0 % 9, c0l = r0 / 9;
            const int k1 = r1 % 9, c1l = r1 / 9;
            const float* x0p = xc + c0l * HWn;
            const float* x1p = xc + c1l * HWn;
            float s0 = w00[k0] * x0p[a00[k0]] + w01[k0] * x0p[a00[k0] + dxk[k0]]
                     + w10[k0] * x0p[a11[k0] - dxk[k0]] + w11[k0] * x0p[a11[k0]];
            float s1 = w00[k1] * x1p[a00[k1]] + w01[k1] * x1p[a00[k1] + dxk[k1]]
                     + w10[k1] * x1p[a11[k1] - dxk[k1]] + w11[k1] * x1p[a11[k1]];
            unsigned pk = (unsigned)(unsigned short)f2bf(s0)
                        | ((unsigned)(unsigned short)f2bf(s1) << 16);
            *(unsigned*)&S[p][grp * 72 + r0] = pk;
        }
        __syncthreads();
        const short* warow = wb + (grp * 32 + (l & 15)) * KCn + cc * 288 + ((l >> 4) * 8);
#pragma unroll
        for (int kk = 0; kk < 9; ++kk) {
            bf16x8 af0 = *(const bf16x8*)(warow + kk * 32);
            bf16x8 af1 = *(const bf16x8*)(warow + 16 * KCn + kk * 32);
            const int kb = kk * 32 + ((l >> 4) * 8);
#pragma unroll
            for (int nf = 0; nf < 4; ++nf) {
                bf16x8 bfg = *(const bf16x8*)&S[nf * 16 + (l & 15)][kb];
                acc[0][nf] = __builtin_amdgcn_mfma_f32_16x16x32_bf16(af0, bfg, acc[0][nf], 0, 0, 0);
                acc[1][nf] = __builtin_amdgcn_mfma_f32_16x16x32_bf16(af1, bfg, acc[1][nf], 0, 0, 0);
            }
        }
        __syncthreads();
    }

    // epilogue: BN + ReLU + residual
#pragma unroll
    for (int mf = 0; mf < 2; ++mf) {
        const int ocb = grp * 32 + mf * 16 + ((l >> 4) << 2);
#pragma unroll
        for (int r = 0; r < 4; ++r) {
            const int oc = ocb + r;
            const float sc = gv[oc] * rsqrtf(vv[oc] + EPSn);
            const float mm = mv[oc], bo = bv[oc];
#pragma unroll
            for (int nf = 0; nf < 4; ++nf) {
                const int pix = pix0 + nf * 16 + (l & 15);
                const int spn = pix - b * HWn;
                const int gidx = b * CHWn + oc * HWn + spn;
                float y = (acc[mf][nf][r] - mm) * sc + bo;
                y = fmaxf(y, 0.f);
                out[gidx] = y + x[gidx];
            }
        }
    }
}

extern "C" void kernel_launch(void* const* d_in, const int* in_sizes, int n_in,
                              void* d_out, int out_size, void* d_ws, size_t ws_size,
                              hipStream_t stream) {
    (void)in_sizes; (void)n_in; (void)out_size; (void)ws_size;

    const float* hu = (const float*)d_in[0];

    char* wsb = (char*)d_ws;
    short* wb    = (short*)wsb;                         // 3 * 147456 shorts
    short* owb   = wb + 3 * Cn * KCn;                   // 3 * 36864 shorts
    float* offb  = (float*)(owb + 3 * 32 * KCn);        // 2*18*9216
    float* maskb = offb + Bn * 18 * HWn;                // 2*9*9216
    float* a1    = maskb + Bn * 9 * HWn;                // Bn*CHWn
    float* a2    = a1 + Bn * CHWn;

    for (int i = 0; i < 3; ++i) {
        cvt_w_kernel<<<(Cn * KCn + 255) / 256, 256, 0, stream>>>(
            (const float*)d_in[3 + 7 * i], wb + i * Cn * KCn);
        cvt_ow_kernel<<<(32 * KCn + 255) / 256, 256, 0, stream>>>(
            (const float*)d_in[1 + 7 * i], owb + i * 32 * KCn);
    }

    const int dils[3] = {2, 4, 8};
    float* outs[3] = {a1, a2, (float*)d_out};
    const float* xin = hu;
    const int nblk = (Bn * HWn) / 64;    // 288

    for (int i = 0; i < 3; ++i) {
        const float* obv = (const float*)d_in[2 + 7 * i];
        const float* gv  = (const float*)d_in[4 + 7 * i];
        const float* bv  = (const float*)d_in[5 + 7 * i];
        const float* mv  = (const float*)d_in[6 + 7 * i];
        const float* vv  = (const float*)d_in[7 + 7 * i];

        offconv_mfma<<<nblk, 256, 0, stream>>>(
            xin, owb + i * 32 * KCn, obv, offb, maskb, dils[i]);
        dconv_mfma<<<nblk, 256, 0, stream>>>(
            xin, offb, maskb, wb + i * Cn * KCn, gv, bv, mv, vv,
            outs[i], dils[i]);
        xin = outs[i];
    }
}

// Round 3
// 351.478 us; speedup vs baseline: 7.5860x; 1.6670x over previous
//
#include <hip/hip_runtime.h>
#include <math.h>

constexpr int Bn  = 2;
constexpr int Cn  = 128;
constexpr int Hn  = 96;
constexpr int Wn  = 96;
constexpr int HWn = Hn * Wn;        // 9216
constexpr int CHWn = Cn * HWn;      // 1179648
constexpr int KCn = Cn * 9;         // 1152
constexpr float EPSn = 1e-5f;
constexpr int KPAD = 1160;          // LDS row stride in shorts (2320B, 2-way on b128)

typedef short bf16x8 __attribute__((ext_vector_type(8)));
typedef float f32x4  __attribute__((ext_vector_type(4)));

static __device__ inline short f2bf(float f) {
    union { float f; unsigned u; } v; v.f = f;
    unsigned r = v.u + 0x7fff + ((v.u >> 16) & 1);
    return (short)(r >> 16);
}

__global__ __launch_bounds__(256) void cvt_w_kernel(
    const float* __restrict__ w, short* __restrict__ wb)
{
    int t = blockIdx.x * 256 + threadIdx.x;   // 128*1152
    if (t < Cn * KCn) wb[t] = f2bf(w[t]);
}

__global__ __launch_bounds__(256) void cvt_ow_kernel(
    const float* __restrict__ ow, short* __restrict__ owb)
{
    int t = blockIdx.x * 256 + threadIdx.x;   // 32*1152
    if (t >= 32 * KCn) return;
    int row = t / KCn;
    owb[t] = (row < 27) ? f2bf(ow[t]) : (short)0;
}

// One fused residual block: offconv(+bias,sigmoid) -> deformable conv -> BN
// -> ReLU -> +residual, for 16 pixels per 256-thread block.
__global__ __launch_bounds__(256) void fused_stage(
    const float* __restrict__ x, const short* __restrict__ wb,
    const short* __restrict__ owb, const float* __restrict__ obv,
    const float* __restrict__ gv, const float* __restrict__ bv,
    const float* __restrict__ mv, const float* __restrict__ vv,
    float* __restrict__ out, int dil)
{
    __shared__ short S[16 * KPAD];          // im2col tile: S[p][ck], 37120B
    __shared__ float offL[16][18];
    __shared__ float maskL[16][9];

    const int t   = threadIdx.x;
    const int l   = t & 63;
    const int wv  = t >> 6;                 // wave id 0..3
    const int p   = t & 15;                 // pixel lane
    const int slc = t >> 4;                 // ck slice 0..15 (72 ck each)

    const int pix0 = blockIdx.x * 16;
    const int b  = pix0 / HWn;
    const int sp = pix0 - b * HWn + p;
    const int hy = sp / Wn;
    const int wx = sp - hy * Wn;

    const float* xb = x + b * CHWn;

    // ---- integer tap setup (per pixel) ----
    int   aof[9];
    float mk[9];
#pragma unroll
    for (int k = 0; k < 9; ++k) {
        int iy = hy + (k / 3 - 1) * dil;
        int ix = wx + (k % 3 - 1) * dil;
        bool v = (iy >= 0) && (iy < Hn) && (ix >= 0) && (ix < Wn);
        aof[k] = v ? iy * Wn + ix : 0;
        mk[k]  = v ? 1.f : 0.f;
    }

    // ---- gather-int: fill S[p][slc*72 .. +71] ----
    {
        const float* xs = xb + slc * 8 * HWn;
#pragma unroll
        for (int j = 0; j < 9; ++j) {
            union { bf16x8 v; short s[8]; } u;
#pragma unroll
            for (int e = 0; e < 8; ++e) {
                const int local = j * 8 + e;
                const int cl = local / 9, k = local % 9;
                float sval = xs[cl * HWn + aof[k]] * mk[k];
                u.s[e] = f2bf(sval);
            }
            *(bf16x8*)&S[p * KPAD + slc * 72 + j * 8] = u.v;
        }
    }
    __syncthreads();

    // ---- offconv GEMM: M=32 (27 used), K split 4 ways across waves ----
    f32x4 oacc0 = {0.f,0.f,0.f,0.f}, oacc1 = {0.f,0.f,0.f,0.f};
    {
        const short* oarow = owb + (l & 15) * KCn + wv * 288 + ((l >> 4) * 8);
#pragma unroll
        for (int kk = 0; kk < 9; ++kk) {
            bf16x8 af0 = *(const bf16x8*)(oarow + kk * 32);
            bf16x8 af1 = *(const bf16x8*)(oarow + 16 * KCn + kk * 32);
            bf16x8 bfg = *(const bf16x8*)&S[(l & 15) * KPAD + wv * 288 + kk * 32 + ((l >> 4) * 8)];
            oacc0 = __builtin_amdgcn_mfma_f32_16x16x32_bf16(af0, bfg, oacc0, 0, 0, 0);
            oacc1 = __builtin_amdgcn_mfma_f32_16x16x32_bf16(af1, bfg, oacc1, 0, 0, 0);
        }
    }
    __syncthreads();                         // S(int) reads done
    float* red = (float*)S;                  // reuse S as 4x2x256 f32 partials
    *(f32x4*)&red[(wv * 2 + 0) * 256 + l * 4] = oacc0;
    *(f32x4*)&red[(wv * 2 + 1) * 256 + l * 4] = oacc1;
    __syncthreads();
    if (wv == 0) {
#pragma unroll
        for (int mf = 0; mf < 2; ++mf) {
            f32x4 s0 = *(const f32x4*)&red[(0 * 2 + mf) * 256 + l * 4];
            f32x4 s1 = *(const f32x4*)&red[(1 * 2 + mf) * 256 + l * 4];
            f32x4 s2 = *(const f32x4*)&red[(2 * 2 + mf) * 256 + l * 4];
            f32x4 s3 = *(const f32x4*)&red[(3 * 2 + mf) * 256 + l * 4];
            f32x4 sm = (s0 + s1) + (s2 + s3);
#pragma unroll
            for (int r = 0; r < 4; ++r) {
                int oc = mf * 16 + ((l >> 4) << 2) + r;
                if (oc < 18) {
                    offL[l & 15][oc] = sm[r] + obv[oc];
                } else if (oc < 27) {
                    float z = sm[r] + obv[oc];
                    maskL[l & 15][oc - 18] = 1.f / (1.f + expf(-z));
                }
            }
        }
    }
    __syncthreads();                         // offL/maskL ready; red dead

    // ---- bilinear params from offL (per pixel) ----
    float w00[9], w01[9], w10[9], w11[9];
    int   a00[9], a11[9], dxk[9];
#pragma unroll
    for (int k = 0; k < 9; ++k) {
        float offy = offL[p][2 * k];
        float offx = offL[p][2 * k + 1];
        float m    = maskL[p][k];
        float py = (float)(hy + (k / 3 - 1) * dil) + offy;
        float px = (float)(wx + (k % 3 - 1) * dil) + offx;
        float y0f = floorf(py), x0f = floorf(px);
        float ly = py - y0f, lx = px - x0f;
        int y0 = (int)y0f, x0 = (int)x0f;
        float yv0 = (y0 >= 0 && y0 < Hn)      ? 1.f : 0.f;
        float yv1 = (y0 >= -1 && y0 < Hn - 1) ? 1.f : 0.f;
        float xv0 = (x0 >= 0 && x0 < Wn)      ? 1.f : 0.f;
        float xv1 = (x0 >= -1 && x0 < Wn - 1) ? 1.f : 0.f;
        float wy0 = (1.f - ly) * yv0 * m;
        float wy1 = ly * yv1 * m;
        float wxa = (1.f - lx) * xv0;
        float wxb = lx * xv1;
        w00[k] = wy0 * wxa; w01[k] = wy0 * wxb;
        w10[k] = wy1 * wxa; w11[k] = wy1 * wxb;
        int y0c = min(max(y0, 0), Hn - 1), y1c = min(max(y0 + 1, 0), Hn - 1);
        int x0c = min(max(x0, 0), Wn - 1), x1c = min(max(x0 + 1, 0), Wn - 1);
        a00[k] = y0c * Wn + x0c;
        a11[k] = y1c * Wn + x1c;
        dxk[k] = x1c - x0c;
    }

    // ---- gather-bil: overwrite S with modulated bilinear samples ----
    {
        const float* xs = xb + slc * 8 * HWn;
#pragma unroll
        for (int j = 0; j < 9; ++j) {
            union { bf16x8 v; short s[8]; } u;
#pragma unroll
            for (int e = 0; e < 8; ++e) {
                const int local = j * 8 + e;
                const int cl = local / 9, k = local % 9;
                const float* xp = xs + cl * HWn;
                float sval = w00[k] * xp[a00[k]] + w01[k] * xp[a00[k] + dxk[k]]
                           + w10[k] * xp[a11[k] - dxk[k]] + w11[k] * xp[a11[k]];
                u.s[e] = f2bf(sval);
            }
            *(bf16x8*)&S[p * KPAD + slc * 72 + j * 8] = u.v;
        }
    }
    __syncthreads();

    // ---- dconv GEMM: wave wv covers output channels wv*32 .. wv*32+31 ----
    f32x4 dacc0 = {0.f,0.f,0.f,0.f}, dacc1 = {0.f,0.f,0.f,0.f};
    {
        const short* darow = wb + (wv * 32 + (l & 15)) * KCn + ((l >> 4) * 8);
#pragma unroll 9
        for (int kk = 0; kk < 36; ++kk) {
            bf16x8 af0 = *(const bf16x8*)(darow + kk * 32);
            bf16x8 af1 = *(const bf16x8*)(darow + 16 * KCn + kk * 32);
            bf16x8 bfg = *(const bf16x8*)&S[(l & 15) * KPAD + kk * 32 + ((l >> 4) * 8)];
            dacc0 = __builtin_amdgcn_mfma_f32_16x16x32_bf16(af0, bfg, dacc0, 0, 0, 0);
            dacc1 = __builtin_amdgcn_mfma_f32_16x16x32_bf16(af1, bfg, dacc1, 0, 0, 0);
        }
    }

    // ---- epilogue: BN + ReLU + residual ----
#pragma unroll
    for (int mf = 0; mf < 2; ++mf) {
        const f32x4 dv = mf ? dacc1 : dacc0;
        const int ocb = wv * 32 + mf * 16 + ((l >> 4) << 2);
#pragma unroll
        for (int r = 0; r < 4; ++r) {
            const int oc = ocb + r;
            const float sc = gv[oc] * rsqrtf(vv[oc] + EPSn);
            const float mm = mv[oc], bo = bv[oc];
            const int gidx = b * CHWn + oc * HWn + (pix0 - b * HWn) + (l & 15);
            float y = (dv[r] - mm) * sc + bo;
            y = fmaxf(y, 0.f);
            out[gidx] = y + x[gidx];
        }
    }
}

extern "C" void kernel_launch(void* const* d_in, const int* in_sizes, int n_in,
                              void* d_out, int out_size, void* d_ws, size_t ws_size,
                              hipStream_t stream) {
    (void)in_sizes; (void)n_in; (void)out_size; (void)ws_size;

    const float* hu = (const float*)d_in[0];

    short* wb    = (short*)d_ws;                        // 3 * 147456 shorts
    short* owb   = wb + 3 * Cn * KCn;                   // 3 * 36864 shorts
    float* a1    = (float*)(owb + 3 * 32 * KCn);        // Bn*CHWn floats
    float* a2    = a1 + Bn * CHWn;

    for (int i = 0; i < 3; ++i) {
        cvt_w_kernel<<<(Cn * KCn + 255) / 256, 256, 0, stream>>>(
            (const float*)d_in[3 + 7 * i], wb + i * Cn * KCn);
        cvt_ow_kernel<<<(32 * KCn + 255) / 256, 256, 0, stream>>>(
            (const float*)d_in[1 + 7 * i], owb + i * 32 * KCn);
    }

    const int dils[3] = {2, 4, 8};
    float* outs[3] = {a1, a2, (float*)d_out};
    const float* xin = hu;
    const int nblk = (Bn * HWn) / 16;    // 1152

    for (int i = 0; i < 3; ++i) {
        const float* obv = (const float*)d_in[2 + 7 * i];
        const float* gv  = (const float*)d_in[4 + 7 * i];
        const float* bv  = (const float*)d_in[5 + 7 * i];
        const float* mv  = (const float*)d_in[6 + 7 * i];
        const float* vv  = (const float*)d_in[7 + 7 * i];

        fused_stage<<<nblk, 256, 0, stream>>>(
            xin, wb + i * Cn * KCn, owb + i * 32 * KCn, obv,
            gv, bv, mv, vv, outs[i], dils[i]);
        xin = outs[i];
    }
}